// Round 5
// baseline (2412.319 us; speedup 1.0000x reference)
//
#include <hip/hip_runtime.h>
#include <math.h>

#define KSIZE 7
#define C_CH  256
#define HW    256
#define BATCH 8

#define TH    32            // output rows per block
#define NT    (HW / TH)     // 8 row-tiles per (n,c) plane

typedef float nfloat4 __attribute__((ext_vector_type(4)));

// ---------------------------------------------------------------------------
// Kernel 1: synthesize the 256 x 7 x 7 Gabor filter bank into d_ws.
// ---------------------------------------------------------------------------
__global__ void gabor_weights_kernel(const float* __restrict__ log_sigma,
                                     const float* __restrict__ log_freq,
                                     const float* __restrict__ theta,
                                     float* __restrict__ gw) {
    int c = threadIdx.x;
    if (c >= C_CH) return;
    float sigma = expf(log_sigma[c]);
    float freq  = expf(log_freq[c]);
    float ct = cosf(theta[c]);
    float st = sinf(theta[c]);
    float inv_sigma = 1.0f / sigma;
    float vals[KSIZE * KSIZE];
    float sum = 0.0f;
    #pragma unroll
    for (int i = 0; i < KSIZE; ++i) {
        #pragma unroll
        for (int j = 0; j < KSIZE; ++j) {
            float dx = (float)(i - 3);
            float dy = (float)(j - 3);
            float x0 = (dx * ct + dy * st) * inv_sigma;
            float x1 = (-dx * st + dy * ct) * inv_sigma;
            float g  = expf(-0.5f * (x0 * x0 + x1 * x1));
            float v  = g * cosf(6.283185307179586f * freq * x0);
            vals[i * KSIZE + j] = v;
            sum += v;
        }
    }
    float inv = 1.0f / sum;
    #pragma unroll
    for (int k = 0; k < KSIZE * KSIZE; ++k)
        gw[c * (KSIZE * KSIZE) + k] = vals[k] * inv;
}

// ---------------------------------------------------------------------------
// Kernel 2: depthwise 7x7 conv, NO LDS, pure TLP streaming.
// Thread (lane, wv): output rows ob..ob+7 (ob = ht*32 + wv*8), cols
// 4*lane..4*lane+3.  Per input row r (14 rows): three 16B-aligned float4
// loads covering cols 4l-4..4l+7; the 5.25x spatial overlap between
// neighboring lanes/waves is served by L1/L2 (38 KB window per block),
// HBM sees each input byte ~once.  Col edges: clamped address + lane-pred
// zero.  Row edges: branch (only rows r<3 / r>10 can be out of image).
// Grid (c, ht, n): flat%8 == c%8 -> all 8 row-tiles of a plane land on
// the same XCD, so halo re-fetches hit that XCD's L2.
// ---------------------------------------------------------------------------
__global__ __launch_bounds__(256, 4)
void gabor_conv_kernel(const float* __restrict__ x,
                       const float* __restrict__ gw,
                       float* __restrict__ out) {
    const int tid  = threadIdx.x;
    const int lane = tid & 63;
    const int wv   = tid >> 6;
    const int c    = blockIdx.x;
    const int ht   = blockIdx.y;
    const int n    = blockIdx.z;

    const size_t plane = ((size_t)n * C_CH + c) * (size_t)(HW * HW);
    const float* xp = x + plane;
    float*       op = out + plane;

    // ---- weights: block-uniform loads -> SGPRs
    float w[KSIZE * KSIZE];
    const float* wp = gw + c * (KSIZE * KSIZE);
    #pragma unroll
    for (int k = 0; k < KSIZE * KSIZE; ++k) w[k] = wp[k];

    const int ob   = ht * TH + wv * 8;   // first output row of this thread
    const int col0 = lane * 4;           // first output col
    const int lcol = (lane == 0)  ? 0   : col0 - 4;   // clamped left-vec col
    const int rcol = (lane == 63) ? 252 : col0 + 4;   // clamped right-vec col

    float acc[8][4];
    #pragma unroll
    for (int o = 0; o < 8; ++o)
        #pragma unroll
        for (int cc = 0; cc < 4; ++cc) acc[o][cc] = 0.f;

    #pragma unroll
    for (int r = 0; r < 14; ++r) {
        const int gr = ob + r - 3;        // input image row
        float4 L, M, R;
        bool in_img = true;
        if (r < 3 || r > 10) in_img = (gr >= 0) && (gr < HW);  // edge rows only
        if (in_img) {
            const float* rp = xp + (size_t)gr * HW;
            L = *reinterpret_cast<const float4*>(rp + lcol);
            M = *reinterpret_cast<const float4*>(rp + col0);
            R = *reinterpret_cast<const float4*>(rp + rcol);
            if (lane == 0)  L = make_float4(0.f, 0.f, 0.f, 0.f);
            if (lane == 63) R = make_float4(0.f, 0.f, 0.f, 0.f);
        } else {
            L = make_float4(0.f, 0.f, 0.f, 0.f);
            M = make_float4(0.f, 0.f, 0.f, 0.f);
            R = make_float4(0.f, 0.f, 0.f, 0.f);
        }
        float f[12] = {L.x, L.y, L.z, L.w, M.x, M.y, M.z, M.w, R.x, R.y, R.z, R.w};

        #pragma unroll
        for (int o = 0; o < 8; ++o) {
            if (o <= r && r <= o + 6) {       // compile-time after unroll
                const int ki = r - o;          // kernel row index 0..6
                #pragma unroll
                for (int cc = 0; cc < 4; ++cc) {
                    #pragma unroll
                    for (int j = 0; j < KSIZE; ++j)
                        acc[o][cc] += f[cc + j + 1] * w[ki * KSIZE + j];
                }
            }
        }
    }

    // ---- store 8 rows x float4, coalesced, nontemporal (pure streaming)
    #pragma unroll
    for (int o = 0; o < 8; ++o) {
        nfloat4 v = {acc[o][0], acc[o][1], acc[o][2], acc[o][3]};
        __builtin_nontemporal_store(v,
            reinterpret_cast<nfloat4*>(op + (size_t)(ob + o) * HW + col0));
    }
}

extern "C" void kernel_launch(void* const* d_in, const int* in_sizes, int n_in,
                              void* d_out, int out_size, void* d_ws, size_t ws_size,
                              hipStream_t stream) {
    const float* x  = (const float*)d_in[0];
    const float* ls = (const float*)d_in[1];
    const float* lf = (const float*)d_in[2];
    const float* th = (const float*)d_in[3];
    float* out = (float*)d_out;
    float* gw  = (float*)d_ws;   // 256*49*4 = 50176 bytes of scratch

    gabor_weights_kernel<<<1, 256, 0, stream>>>(ls, lf, th, gw);

    dim3 grid(C_CH, NT, BATCH);   // (c, ht, n): plane's tiles share an XCD
    gabor_conv_kernel<<<grid, 256, 0, stream>>>(x, gw, out);
}

// Round 6
// 624.742 us; speedup vs baseline: 3.8613x; 3.8613x over previous
//
#include <hip/hip_runtime.h>
#include <math.h>

#define KSIZE 7
#define C_CH  256
#define HW    256
#define BATCH 8

#define TH    32            // output rows per tile
#define ROWS  (TH + 6)      // 38 input rows staged (3-row halo each side)
#define LDW   264           // 4 zero + 256 + 4 zero padded floats per LDS row
#define NT    (HW / TH)     // 8 tiles per (n,c) plane

// ---------------------------------------------------------------------------
// Kernel 1: synthesize the 256 x 7 x 7 Gabor filter bank into d_ws.
// ---------------------------------------------------------------------------
__global__ void gabor_weights_kernel(const float* __restrict__ log_sigma,
                                     const float* __restrict__ log_freq,
                                     const float* __restrict__ theta,
                                     float* __restrict__ gw) {
    int c = threadIdx.x;
    if (c >= C_CH) return;
    float sigma = expf(log_sigma[c]);
    float freq  = expf(log_freq[c]);
    float ct = cosf(theta[c]);
    float st = sinf(theta[c]);
    float inv_sigma = 1.0f / sigma;
    float vals[KSIZE * KSIZE];
    float sum = 0.0f;
    #pragma unroll
    for (int i = 0; i < KSIZE; ++i) {
        #pragma unroll
        for (int j = 0; j < KSIZE; ++j) {
            float dx = (float)(i - 3);
            float dy = (float)(j - 3);
            float x0 = (dx * ct + dy * st) * inv_sigma;
            float x1 = (-dx * st + dy * ct) * inv_sigma;
            float g  = expf(-0.5f * (x0 * x0 + x1 * x1));
            float v  = g * cosf(6.283185307179586f * freq * x0);
            vals[i * KSIZE + j] = v;
            sum += v;
        }
    }
    float inv = 1.0f / sum;
    #pragma unroll
    for (int k = 0; k < KSIZE * KSIZE; ++k)
        gw[c * (KSIZE * KSIZE) + k] = vals[k] * inv;
}

// ---------------------------------------------------------------------------
// Kernel 2: depthwise 7x7 conv; persistent block per (n,c) plane.
// m201-style pipeline per tile:
//   [all 42 ds_read_b128 -> regs] -> fence -> [stage next: halo LDS copy +
//   8 global_load_lds/wave into the OTHER shared array] -> fence ->
//   [1568 FMAs] -> [8 stores] -> s_waitcnt vmcnt(8) -> s_barrier.
// ds_reads precede the stage issues, so no wait can couple compute to the
// in-flight prefetch; vmcnt(8) drains the gloads but not this tile's stores.
// 2 blocks/CU (LDS 2x80KB) = 2 waves/SIMD, so the ~210-VGPR register file
// for the 42 staged float4s costs no occupancy.
// ---------------------------------------------------------------------------
__device__ __forceinline__ void gload_lds16(const float* g, float* l) {
    __builtin_amdgcn_global_load_lds(
        (const __attribute__((address_space(1))) void*)g,
        (__attribute__((address_space(3))) void*)l,
        16, 0, 0);
}

#define FCOMP(v, k) ((k) == 0 ? (v).x : ((k) == 1 ? (v).y : ((k) == 2 ? (v).z : (v).w)))
#define FF(r, k) FCOMP(f4[r][(k) >> 2], (k) & 3)

template <int T>
__device__ __forceinline__ void conv_iter(float (&CURB)[ROWS][LDW],
                                          float (&NXTB)[ROWS][LDW],
                                          const float* __restrict__ xp,
                                          float* __restrict__ op,
                                          const float (&w)[KSIZE * KSIZE],
                                          int tid, int lane, int wv,
                                          int colp, int ob) {
    // ---- 1. read this tile's full register window FIRST (42 x ds_read_b128)
    float4 f4[14][3];
    #pragma unroll
    for (int r = 0; r < 14; ++r) {
        f4[r][0] = *reinterpret_cast<const float4*>(&CURB[ob + r][colp]);
        f4[r][1] = *reinterpret_cast<const float4*>(&CURB[ob + r][colp + 4]);
        f4[r][2] = *reinterpret_cast<const float4*>(&CURB[ob + r][colp + 8]);
    }
    asm volatile("" ::: "memory");   // reads stay above the stage issues

    // ---- 2. stage next tile into the OTHER buffer
    if (T + 1 < NT) {
        // halo: rows 0..5 of next = rows 32..37 of current (LDS->LDS)
        #pragma unroll
        for (int i2 = tid; i2 < 6 * 64; i2 += 256) {
            int r2 = i2 >> 6, q2 = i2 & 63;
            *reinterpret_cast<float4*>(&NXTB[r2][4 + q2 * 4]) =
                *reinterpret_cast<const float4*>(&CURB[32 + r2][4 + q2 * 4]);
        }
        if (T + 1 == NT - 1) {        // bottom-of-image zeros
            #pragma unroll
            for (int i2 = tid; i2 < 3 * 64; i2 += 256) {
                int r2 = 35 + (i2 >> 6), q2 = i2 & 63;
                *reinterpret_cast<float4*>(&NXTB[r2][4 + q2 * 4]) =
                    make_float4(0.f, 0.f, 0.f, 0.f);
            }
        }
        const int row0 = (T + 1) * TH - 3;
        const int rmax = (T + 1 == NT - 1) ? 34 : 37;
        for (int rr = 6 + wv; rr <= rmax; rr += 4)
            gload_lds16(xp + (size_t)(row0 + rr) * HW + lane * 4, &NXTB[rr][4]);
    }
    asm volatile("" ::: "memory");   // stores below stay below the gloads

    // ---- 3. compute 8 rows x 4 cols
    float acc[8][4];
    #pragma unroll
    for (int o = 0; o < 8; ++o)
        #pragma unroll
        for (int cc = 0; cc < 4; ++cc) acc[o][cc] = 0.f;

    #pragma unroll
    for (int r = 0; r < 14; ++r) {
        #pragma unroll
        for (int o = 0; o < 8; ++o) {
            if (o <= r && r <= o + 6) {
                const int ki = r - o;
                #pragma unroll
                for (int cc = 0; cc < 4; ++cc) {
                    #pragma unroll
                    for (int j = 0; j < KSIZE; ++j)
                        acc[o][cc] += FF(r, cc + j + 1) * w[ki * KSIZE + j];
                }
            }
        }
    }

    // ---- 4. store 8 rows x float4 (issued after the gloads)
    const int orow0 = T * TH + ob;
    #pragma unroll
    for (int o = 0; o < 8; ++o) {
        float4 v = make_float4(acc[o][0], acc[o][1], acc[o][2], acc[o][3]);
        *reinterpret_cast<float4*>(op + (size_t)(orow0 + o) * HW + colp) = v;
    }

    // ---- 5. counted wait: drain gloads (older), keep stores in flight
    if (T + 1 < NT) {
        asm volatile("s_waitcnt vmcnt(8)" ::: "memory");
        __builtin_amdgcn_s_barrier();
    }
}

__global__ __launch_bounds__(256, 2)
void gabor_conv_kernel(const float* __restrict__ x,
                       const float* __restrict__ gw,
                       float* __restrict__ out) {
    __shared__ __align__(16) float tA[ROWS][LDW];
    __shared__ __align__(16) float tB[ROWS][LDW];

    const int tid  = threadIdx.x;
    const int lane = tid & 63;
    const int wv   = tid >> 6;
    const int c    = blockIdx.x;
    const int n    = blockIdx.y;

    const size_t plane = ((size_t)n * C_CH + c) * (size_t)(HW * HW);
    const float* xp = x + plane;
    float*       op = out + plane;

    // ---- zero the pad columns of BOTH buffers once
    for (int idx = tid; idx < 2 * ROWS; idx += 256) {
        int b  = idx / ROWS;
        int rr = idx - b * ROWS;
        float4 z = make_float4(0.f, 0.f, 0.f, 0.f);
        if (b == 0) {
            *reinterpret_cast<float4*>(&tA[rr][0])   = z;
            *reinterpret_cast<float4*>(&tA[rr][260]) = z;
        } else {
            *reinterpret_cast<float4*>(&tB[rr][0])   = z;
            *reinterpret_cast<float4*>(&tB[rr][260]) = z;
        }
    }

    // ---- weights (block-uniform -> scalar regs)
    float w[KSIZE * KSIZE];
    const float* wp = gw + c * (KSIZE * KSIZE);
    #pragma unroll
    for (int k = 0; k < KSIZE * KSIZE; ++k) w[k] = wp[k];

    // ---- prologue: stage tile 0 into tA (rows 0..2 zero, 3..37 gloads)
    for (int i = tid; i < 3 * 64; i += 256) {
        int r = i >> 6, q = i & 63;
        *reinterpret_cast<float4*>(&tA[r][4 + q * 4]) = make_float4(0.f, 0.f, 0.f, 0.f);
    }
    for (int rr = 3 + wv; rr < ROWS; rr += 4)
        gload_lds16(xp + (size_t)(rr - 3) * HW + lane * 4, &tA[rr][4]);
    asm volatile("s_waitcnt vmcnt(0) lgkmcnt(0)" ::: "memory");
    __builtin_amdgcn_s_barrier();

    const int colp = lane * 4;
    const int ob   = wv * 8;

    conv_iter<0>(tA, tB, xp, op, w, tid, lane, wv, colp, ob);
    conv_iter<1>(tB, tA, xp, op, w, tid, lane, wv, colp, ob);
    conv_iter<2>(tA, tB, xp, op, w, tid, lane, wv, colp, ob);
    conv_iter<3>(tB, tA, xp, op, w, tid, lane, wv, colp, ob);
    conv_iter<4>(tA, tB, xp, op, w, tid, lane, wv, colp, ob);
    conv_iter<5>(tB, tA, xp, op, w, tid, lane, wv, colp, ob);
    conv_iter<6>(tA, tB, xp, op, w, tid, lane, wv, colp, ob);
    conv_iter<7>(tB, tA, xp, op, w, tid, lane, wv, colp, ob);
}

extern "C" void kernel_launch(void* const* d_in, const int* in_sizes, int n_in,
                              void* d_out, int out_size, void* d_ws, size_t ws_size,
                              hipStream_t stream) {
    const float* x  = (const float*)d_in[0];
    const float* ls = (const float*)d_in[1];
    const float* lf = (const float*)d_in[2];
    const float* th = (const float*)d_in[3];
    float* out = (float*)d_out;
    float* gw  = (float*)d_ws;   // 256*49*4 = 50176 bytes of scratch

    gabor_weights_kernel<<<1, 256, 0, stream>>>(ls, lf, th, gw);

    dim3 grid(C_CH, BATCH);      // one persistent block per (n,c) plane
    gabor_conv_kernel<<<grid, 256, 0, stream>>>(x, gw, out);
}